// Round 4
// baseline (2640.937 us; speedup 1.0000x reference)
//
#include <hip/hip_runtime.h>
#include <hip/hip_bf16.h>

using u16 = unsigned short;
using u32 = unsigned int;

#define BB 512
#define SS 100
#define LL 30
#define DD 400
#define MM 128
#define HH 20
#define DHH 20

__device__ __forceinline__ float lo2f(u32 u) { return __uint_as_float(u << 16); }
__device__ __forceinline__ float hi2f(u32 u) { return __uint_as_float(u & 0xffff0000u); }
__device__ __forceinline__ float bf2f(u16 h) { return __uint_as_float(((u32)h) << 16); }

// ---------------------------------------------------------------------------
// K0: input dtype detection (flag: 0 = bf16, 1 = f32).  For a bf16 tensor the
// low 16 bits of each u32 word are a bf16 of N(0,~0.02): exponent bits in
// [100,128] nearly always.  For f32 those bits are uniform mantissa (~11%).
// ---------------------------------------------------------------------------
__global__ __launch_bounds__(256) void k_detect(const u32* __restrict__ emb,
                                                u32* __restrict__ flag) {
  __shared__ int cnt;
  const int t = threadIdx.x;
  if (t == 0) cnt = 0;
  __syncthreads();
  const u32 w = emb[t] & 0xffffu;
  const int e = (int)((w >> 7) & 0xff);
  if (e >= 100 && e <= 128) atomicAdd(&cnt, 1);
  __syncthreads();
  if (t == 0) *flag = (cnt < 128) ? 1u : 0u;
}

// ---------------------------------------------------------------------------
// K1: embedding gather + mean pool for one chunk.  wave-per-(b,s) row.
// click written f32 [CR,400] chunk-local.
// ---------------------------------------------------------------------------
__global__ __launch_bounds__(256) void k_embed(const int* __restrict__ uc,
                                               const void* __restrict__ emb,
                                               float* __restrict__ click,
                                               const u32* __restrict__ flag, int b0) {
  const int wave = threadIdx.x >> 6, lane = threadIdx.x & 63;
  const int bsl = blockIdx.x * 4 + wave;      // chunk-local (b,s) row
  const int bs  = b0 * SS + bsl;              // global (b,s) row
  __shared__ int rows[4][LL];
  if (lane < LL) rows[wave][lane] = uc[(size_t)bs * LL + lane];
  __syncthreads();
  const float sc = 1.0f / (float)LL;
  float* orow = click + (size_t)bsl * DD;
  if (*flag != 0u) {  // ---- f32 table ----
    const float* ef = (const float*)emb;
    float a[7] = {0.f, 0.f, 0.f, 0.f, 0.f, 0.f, 0.f};
    for (int l = 0; l < LL; ++l) {
      const float* row = ef + (size_t)rows[wave][l] * DD;
#pragma unroll
      for (int j = 0; j < 6; ++j) a[j] += row[lane + j * 64];
      if (lane < 16) a[6] += row[lane + 384];
    }
#pragma unroll
    for (int j = 0; j < 6; ++j) orow[lane + j * 64] = a[j] * sc;
    if (lane < 16) orow[lane + 384] = a[6] * sc;
  } else {            // ---- bf16 table (fallback) ----
    const u16* e16 = (const u16*)emb;
    float ax[4] = {0.f, 0.f, 0.f, 0.f}, ay[4] = {0.f, 0.f, 0.f, 0.f};
    for (int l = 0; l < LL; ++l) {
      const u32* row = (const u32*)(e16 + (size_t)rows[wave][l] * DD);
      const u32 a = row[lane], b = row[lane + 64], c = row[lane + 128];
      ax[0] += lo2f(a); ay[0] += hi2f(a);
      ax[1] += lo2f(b); ay[1] += hi2f(b);
      ax[2] += lo2f(c); ay[2] += hi2f(c);
      if (lane < 8) { const u32 d = row[lane + 192]; ax[3] += lo2f(d); ay[3] += hi2f(d); }
    }
#pragma unroll
    for (int j = 0; j < 3; ++j) {
      float2* dst = (float2*)&orow[2 * (lane + j * 64)];
      *dst = make_float2(ax[j] * sc, ay[j] * sc);
    }
    if (lane < 8) {
      float2* dst = (float2*)&orow[2 * (lane + 192)];
      *dst = make_float2(ax[3] * sc, ay[3] * sc);
    }
  }
}

// ---------------------------------------------------------------------------
// K2: QKV projection GEMM for one chunk (chunk-local f32 in and out).
// [CR,400] x [400,400]x3; nt/10 selects q/k/v, nt%10 the 40-col tile.
// 64x40 tile, K-chunk 40, stride-42 LDS pad.
// ---------------------------------------------------------------------------
__global__ __launch_bounds__(320) void k_qkv(const float* __restrict__ click,
    const void* __restrict__ wq, const void* __restrict__ wk, const void* __restrict__ wv,
    float* __restrict__ qo, float* __restrict__ ko, float* __restrict__ vo,
    const u32* __restrict__ flag) {
  __shared__ float As[64][42];
  __shared__ float Ws[40][42];
  const int t = threadIdx.x;
  const int mt = blockIdx.x, nt = blockIdx.y;
  const int mat = nt / 10;
  const int wcol = (nt % 10) * 40;
  const void* W = (mat == 0) ? wq : ((mat == 1) ? wk : wv);
  float* O = (mat == 0) ? qo : ((mat == 1) ? ko : vo);
  const int row0 = mt * 64;
  const int c0 = (t % 20) * 2;
  const int r0 = (t / 20) * 4;
  const bool is32 = (*flag != 0u);
  float acc[4][2] = {{0.f,0.f},{0.f,0.f},{0.f,0.f},{0.f,0.f}};
  for (int kt = 0; kt < DD; kt += 40) {
#pragma unroll
    for (int i = 0; i < 4; ++i) {           // A tile: 64x40 f32 = 1280 float2
      const int id = t + i * 320;
      const int r = id / 20, pk = id % 20;
      const float2 u = *(const float2*)&click[(size_t)(row0 + r) * DD + kt + pk * 2];
      *(float2*)&As[r][pk * 2] = u;
    }
    if (is32) {                              // W tile: 40x40 f32 = 800 float2
#pragma unroll
      for (int i = 0; i < 3; ++i) {
        const int id = t + i * 320;
        if (id < 800) {
          const int r = id / 20, pk = id % 20;
          const float2 u = *(const float2*)((const float*)W + (size_t)(kt + r) * DD + wcol + pk * 2);
          *(float2*)&Ws[r][pk * 2] = u;
        }
      }
    } else {
#pragma unroll
      for (int i = 0; i < 3; ++i) {
        const int id = t + i * 320;
        if (id < 800) {
          const int r = id / 20, pk = id % 20;
          const u32 u = *(const u32*)((const u16*)W + (size_t)(kt + r) * DD + wcol + pk * 2);
          *(float2*)&Ws[r][pk * 2] = make_float2(lo2f(u), hi2f(u));
        }
      }
    }
    __syncthreads();
#pragma unroll 8
    for (int kk = 0; kk < 40; ++kk) {
      const float w0 = Ws[kk][c0], w1 = Ws[kk][c0 + 1];
#pragma unroll
      for (int i = 0; i < 4; ++i) {
        const float a = As[r0 + i][kk];
        acc[i][0] += a * w0;
        acc[i][1] += a * w1;
      }
    }
    __syncthreads();
  }
#pragma unroll
  for (int i = 0; i < 4; ++i) {
    const int row = row0 + r0 + i;
    *(float2*)&O[(size_t)row * DD + wcol + c0] = make_float2(acc[i][0], acc[i][1]);
  }
}

// ---------------------------------------------------------------------------
// K3: fused per-(b,h) self-attention for one chunk (chunk-local f32).
// q/k/v/logits in LDS (65.6 KB); ctx written chunk-local f32.
// ---------------------------------------------------------------------------
__global__ __launch_bounds__(256) void k_attn(const float* __restrict__ qg,
    const float* __restrict__ kg, const float* __restrict__ vg,
    const int* __restrict__ seq, float* __restrict__ ctxg, int b0) {
  const int bl = blockIdx.x / HH, h = blockIdx.x % HH;
  const int t = threadIdx.x;
  __shared__ float qs[SS][21], ks[SS][21], vs[SS][20];
  __shared__ float lg[SS][101];
  const int len = seq[b0 + bl];
  for (int id = t; id < SS * DHH; id += 256) {   // scalar staging (odd pad)
    const int s = id / DHH, j = id % DHH;
    const size_t off = (size_t)(bl * SS + s) * DD + h * DHH + j;
    qs[s][j] = qg[off];
    ks[s][j] = kg[off];
    vs[s][j] = vg[off];
  }
  __syncthreads();
  const float sc = 0.2236067977499790f;  // 1/sqrt(20)
  for (int p = t; p < SS * SS; p += 256) {
    const int sq = p / SS, sk = p % SS;
    float acc = 0.f;
#pragma unroll
    for (int j = 0; j < DHH; ++j) acc += qs[sq][j] * ks[sk][j];
    lg[sq][sk] = acc * sc + ((sk < len) ? 1.0f : -1e9f);
  }
  __syncthreads();
  if (t < SS) {
    float mx = -3.0e38f;
    for (int j = 0; j < SS; ++j) mx = fmaxf(mx, lg[t][j]);
    float sum = 0.f;
    for (int j = 0; j < SS; ++j) { const float ex = __expf(lg[t][j] - mx); lg[t][j] = ex; sum += ex; }
    const float inv = 1.0f / sum;
    for (int j = 0; j < SS; ++j) lg[t][j] *= inv;
  }
  __syncthreads();
  for (int id = t; id < SS * 10; id += 256) {
    const int s = id / 10, pj = id % 10;
    float a0 = 0.f, a1 = 0.f;
    for (int kk = 0; kk < SS; ++kk) {
      const float p = lg[s][kk];
      a0 += p * vs[kk][pj * 2];
      a1 += p * vs[kk][pj * 2 + 1];
    }
    *(float2*)&ctxg[(size_t)(bl * SS + s) * DD + h * DHH + pj * 2] = make_float2(a0, a1);
  }
}

// ---------------------------------------------------------------------------
// K4: e = tanh(ctx @ fc1_w + fc1_b) for one chunk (chunk-local f32).
// ---------------------------------------------------------------------------
__global__ __launch_bounds__(256) void k_fc1(const float* __restrict__ ctxg,
    const void* __restrict__ f1w, const void* __restrict__ f1b, float* __restrict__ e,
    const u32* __restrict__ flag) {
  __shared__ float As[32][DD];
  const int t = threadIdx.x;
  const int row0 = blockIdx.x * 32;
#pragma unroll
  for (int i = 0; i < 25; ++i) {           // 32x400 f32 = 6400 float2
    const int id = t + i * 256;
    const int r = id / 200, pk = id % 200;
    *(float2*)&As[r][pk * 2] = *(const float2*)&ctxg[(size_t)(row0 + r) * DD + pk * 2];
  }
  __syncthreads();
  const int c = t & 127, g = t >> 7;
  const int r0 = g * 16;
  const bool is32 = (*flag != 0u);
  float acc[16];
#pragma unroll
  for (int r = 0; r < 16; ++r) acc[r] = 0.f;
  if (is32) {
    const float* fw = (const float*)f1w;
    for (int d = 0; d < DD; d += 4) {
      const float w0 = fw[(d + 0) * MM + c];
      const float w1 = fw[(d + 1) * MM + c];
      const float w2 = fw[(d + 2) * MM + c];
      const float w3 = fw[(d + 3) * MM + c];
#pragma unroll
      for (int r = 0; r < 16; ++r) {
        const float4 a = *(const float4*)&As[r0 + r][d];
        acc[r] += a.x * w0 + a.y * w1 + a.z * w2 + a.w * w3;
      }
    }
  } else {
    const u16* fw = (const u16*)f1w;
    for (int d = 0; d < DD; d += 4) {
      const float w0 = bf2f(fw[(d + 0) * MM + c]);
      const float w1 = bf2f(fw[(d + 1) * MM + c]);
      const float w2 = bf2f(fw[(d + 2) * MM + c]);
      const float w3 = bf2f(fw[(d + 3) * MM + c]);
#pragma unroll
      for (int r = 0; r < 16; ++r) {
        const float4 a = *(const float4*)&As[r0 + r][d];
        acc[r] += a.x * w0 + a.y * w1 + a.z * w2 + a.w * w3;
      }
    }
  }
  const float bias = is32 ? ((const float*)f1b)[c] : bf2f(((const u16*)f1b)[c]);
#pragma unroll
  for (int r = 0; r < 16; ++r) {
    e[(size_t)(row0 + r0 + r) * MM + c] = tanhf(acc[r] + bias);
  }
}

// ---------------------------------------------------------------------------
// K5: additive attention pooling for one chunk.  One block per batch row.
// Output written f32 at global rows.
// ---------------------------------------------------------------------------
__global__ __launch_bounds__(256) void k_pool(const float* __restrict__ e,
    const void* __restrict__ f2w, const void* __restrict__ f2b,
    const int* __restrict__ seq, const float* __restrict__ ctxg, float* __restrict__ out,
    const u32* __restrict__ flag, int b0) {
  const int bl = blockIdx.x;
  const int b = b0 + bl;
  const int t = threadIdx.x, w = t >> 6, lane = t & 63;
  __shared__ float wts[SS];
  __shared__ float fw[MM];
  const bool is32 = (*flag != 0u);
  if (t < MM) fw[t] = is32 ? ((const float*)f2w)[t] : bf2f(((const u16*)f2w)[t]);
  __syncthreads();
  const int len = seq[b];
  const float bias = is32 ? ((const float*)f2b)[0] : bf2f(((const u16*)f2b)[0]);
  for (int s = w; s < SS; s += 4) {
    const float* er = e + (size_t)(bl * SS + s) * MM;
    float p = er[lane] * fw[lane] + er[lane + 64] * fw[lane + 64];
#pragma unroll
    for (int o = 32; o > 0; o >>= 1) p += __shfl_down(p, o);
    if (lane == 0) wts[s] = p + bias + ((s < len) ? 1.0f : -1e9f);
  }
  __syncthreads();
  if (w == 0) {
    const float v0 = wts[lane];
    const float v1 = (lane + 64 < SS) ? wts[lane + 64] : -3.0e38f;
    float mx = fmaxf(v0, v1);
#pragma unroll
    for (int o = 32; o > 0; o >>= 1) mx = fmaxf(mx, __shfl_xor(mx, o));
    const float e0 = __expf(v0 - mx);
    const float e1 = (lane + 64 < SS) ? __expf(v1 - mx) : 0.f;
    float sm = e0 + e1;
#pragma unroll
    for (int o = 32; o > 0; o >>= 1) sm += __shfl_xor(sm, o);
    const float inv = 1.0f / sm;
    wts[lane] = e0 * inv;
    if (lane + 64 < SS) wts[lane + 64] = e1 * inv;
  }
  __syncthreads();
  for (int d = t; d < DD; d += 256) {
    float acc = 0.f;
    const float* cb = ctxg + (size_t)bl * SS * DD + d;
    for (int s = 0; s < SS; ++s) acc += wts[s] * cb[(size_t)s * DD];
    out[(size_t)b * DD + d] = acc;
  }
}

// ---------------------------------------------------------------------------
// Fully chunked pipeline, all-f32.  Chunk size BC picked from ws_size.
// Per-chunk f32 buffers (CR = BC*100 rows):
//   click/ctx [CR,400] (shared: click dead after qkv, attn writes ctx there is
//   NOT safe -> separate ctx? No: attn reads q/k/v only, so ctx CAN overlay
//   click)  -- layout: click(=ctx) | q | k | v ; e overlays q (dead after attn).
// Footprint = (64 + CR*1600)*4 B:  BC=512 -> 328 MB ... BC=16 -> 10.2 MB.
// ---------------------------------------------------------------------------
extern "C" void kernel_launch(void* const* d_in, const int* in_sizes, int n_in,
                              void* d_out, int out_size, void* d_ws, size_t ws_size,
                              hipStream_t stream) {
  const int* uc  = (const int*)d_in[0];
  const int* seq = (const int*)d_in[1];
  const void* emb = d_in[2];
  const void* wq  = d_in[3];
  const void* wk  = d_in[4];
  const void* wv  = d_in[5];
  const void* f1w = d_in[6];
  const void* f1b = d_in[7];
  const void* f2w = d_in[8];
  const void* f2b = d_in[9];
  float* out = (float*)d_out;

  int BC = 512;
  auto need = [](int bc) { return (size_t)(64 + (size_t)bc * 100 * 1600) * 4; };
  while (BC > 16 && need(BC) > ws_size) BC >>= 1;
  const int CR = BC * SS;
  const int NC = BB / BC;

  float* base   = (float*)d_ws;
  u32*   flag   = (u32*)d_ws;
  float* clickc = base + 64;                 // also ctx
  float* qc     = clickc + (size_t)CR * DD;
  float* kc     = qc + (size_t)CR * DD;
  float* vc     = kc + (size_t)CR * DD;
  float* ec     = qc;                        // q dead after attn

  k_detect<<<1, 256, 0, stream>>>((const u32*)emb, flag);
  for (int c = 0; c < NC; ++c) {
    const int b0 = c * BC;
    k_embed<<<CR / 4, 256, 0, stream>>>(uc, emb, clickc, flag, b0);
    k_qkv<<<dim3(CR / 64, 30), 320, 0, stream>>>(clickc, wq, wk, wv, qc, kc, vc, flag);
    k_attn<<<BC * HH, 256, 0, stream>>>(qc, kc, vc, seq, clickc, b0);
    k_fc1<<<CR / 32, 256, 0, stream>>>(clickc, f1w, f1b, ec, flag);
    k_pool<<<BC, 256, 0, stream>>>(ec, f2w, f2b, seq, clickc, out, flag, b0);
  }
}

// Round 5
// 1049.539 us; speedup vs baseline: 2.5163x; 2.5163x over previous
//
#include <hip/hip_runtime.h>
#include <hip/hip_bf16.h>

using u16 = unsigned short;
using u32 = unsigned int;

#define BB 512
#define SS 100
#define LL 30
#define DD 400
#define MM 128
#define HH 20
#define DHH 20

typedef short v8s __attribute__((ext_vector_type(8)));   // 8 bf16 = 4 VGPR
typedef float v4f __attribute__((ext_vector_type(4)));   // MFMA 16x16 acc

__device__ __forceinline__ float lo2f(u32 u) { return __uint_as_float(u << 16); }
__device__ __forceinline__ float hi2f(u32 u) { return __uint_as_float(u & 0xffff0000u); }
__device__ __forceinline__ float bf2f(u16 h) { return __uint_as_float(((u32)h) << 16); }
__device__ __forceinline__ u16 f2bf(float f) {
  u32 u = __float_as_uint(f);
  u += 0x7fffu + ((u >> 16) & 1u);
  return (u16)(u >> 16);
}
__device__ __forceinline__ u32 packf2(float a, float b) {
  return (u32)f2bf(a) | (((u32)f2bf(b)) << 16);
}

// ---------------------------------------------------------------------------
// K0a: f32 -> bf16 bulk convert (emb table).  n4 = elements/4.
// ---------------------------------------------------------------------------
__global__ __launch_bounds__(256) void k_cvt(const float* __restrict__ src,
                                             u16* __restrict__ dst, int n4) {
  const int i = blockIdx.x * 256 + threadIdx.x;
  if (i < n4) {
    const float4 v = ((const float4*)src)[i];
    ((uint2*)dst)[i] = make_uint2(packf2(v.x, v.y), packf2(v.z, v.w));
  }
}

// ---------------------------------------------------------------------------
// K0b: transpose-convert  src f32 [K][N]  ->  dst bf16 [N][K].
// grid (ceil(N/32), ceil(K/32)), 256 threads.
// ---------------------------------------------------------------------------
__global__ __launch_bounds__(256) void k_trans(const float* __restrict__ src,
                                               u16* __restrict__ dst, int K, int N) {
  __shared__ float ts[32][33];
  const int t = threadIdx.x;
  const int n0 = blockIdx.x * 32, k0 = blockIdx.y * 32;
  const int c = t & 31, r8 = t >> 5;
#pragma unroll
  for (int i = 0; i < 4; ++i) {
    const int k = k0 + r8 + i * 8, n = n0 + c;
    ts[r8 + i * 8][c] = (k < K && n < N) ? src[(size_t)k * N + n] : 0.f;
  }
  __syncthreads();
#pragma unroll
  for (int i = 0; i < 4; ++i) {
    const int n = n0 + r8 + i * 8, k = k0 + c;
    if (n < N && k < K) dst[(size_t)n * K + k] = f2bf(ts[c][r8 + i * 8]);
  }
}

// ---------------------------------------------------------------------------
// K1: embedding gather + mean pool (bf16 table).  wave-per-(b,s) row;
// click written bf16-packed u32 [51200][200].
// ---------------------------------------------------------------------------
__global__ __launch_bounds__(256) void k_embed(const int* __restrict__ uc,
                                               const u16* __restrict__ emb,
                                               u32* __restrict__ click) {
  const int wave = threadIdx.x >> 6, lane = threadIdx.x & 63;
  const int bs = blockIdx.x * 4 + wave;
  __shared__ int rows[4][LL];
  if (lane < LL) rows[wave][lane] = uc[(size_t)bs * LL + lane];
  __syncthreads();
  float ax[4] = {0.f, 0.f, 0.f, 0.f}, ay[4] = {0.f, 0.f, 0.f, 0.f};
  for (int l = 0; l < LL; ++l) {
    const u32* row = (const u32*)(emb + (size_t)rows[wave][l] * DD);
    const u32 a = row[lane], b = row[lane + 64], c = row[lane + 128];
    ax[0] += lo2f(a); ay[0] += hi2f(a);
    ax[1] += lo2f(b); ay[1] += hi2f(b);
    ax[2] += lo2f(c); ay[2] += hi2f(c);
    if (lane < 8) { const u32 d = row[lane + 192]; ax[3] += lo2f(d); ay[3] += hi2f(d); }
  }
  const float s = 1.0f / (float)LL;
  u32* orow = click + (size_t)bs * 200;
  orow[lane]       = packf2(ax[0] * s, ay[0] * s);
  orow[lane + 64]  = packf2(ax[1] * s, ay[1] * s);
  orow[lane + 128] = packf2(ax[2] * s, ay[2] * s);
  if (lane < 8) orow[lane + 192] = packf2(ax[3] * s, ay[3] * s);
}

// ---------------------------------------------------------------------------
// K2: QKV projection, bf16 MFMA.  C[m][n] = sum_k A[m][k] * Wt[n][k].
// A = click16 [51200][400], Wt = [1200][400] (rows 0-399 wq^T, 400-799 wk^T,
// 800-1199 wv^T).  Block tile 256M x 80N, K-chunk 32 (13 chunks, zero-pad
// to 416).  4 waves; wave = 64M x 80N = 4x5 16x16 tiles.
// grid (200, 15): y -> mat = y/5, ntile = y%5.
// ---------------------------------------------------------------------------
__global__ __launch_bounds__(256) void k_qkv_mfma(const u16* __restrict__ A,
    const u16* __restrict__ Wt, u16* __restrict__ qo, u16* __restrict__ ko_,
    u16* __restrict__ vo) {
  __shared__ u16 As[256][40];   // 32 + 8 pad  (stride 80 B: 2 lanes/bank = free)
  __shared__ u16 Bs[80][40];
  const int t = threadIdx.x;
  const int wave = t >> 6, lane = t & 63;
  const int q = lane >> 4, l16 = lane & 15;
  const int m0 = blockIdx.x * 256;
  const int mat = blockIdx.y / 5, ntile = blockIdx.y % 5;
  const int nb = ntile * 80;
  const u16* Bt = Wt + (size_t)(mat * 400 + nb) * 400;
  u16* O = (mat == 0) ? qo : ((mat == 1) ? ko_ : vo);
  const int mw = wave * 64;

  v4f acc[4][5];
#pragma unroll
  for (int i = 0; i < 4; ++i)
#pragma unroll
    for (int j = 0; j < 5; ++j) acc[i][j] = (v4f){0.f, 0.f, 0.f, 0.f};

  for (int kt = 0; kt < 13; ++kt) {
    const int k0 = kt * 32;
    // stage A: 256 rows x 32 bf16 (1024 x 16B loads, 4 per thread)
#pragma unroll
    for (int i = 0; i < 4; ++i) {
      const int id = i * 256 + t;
      const int r = id >> 2, ko = (id & 3) * 8;
      uint4 val = make_uint4(0u, 0u, 0u, 0u);
      if (k0 + ko < 400) val = *(const uint4*)&A[(size_t)(m0 + r) * 400 + k0 + ko];
      *(uint4*)&As[r][ko] = val;
    }
    // stage B: 80 rows x 32 bf16 (320 x 16B loads)
#pragma unroll
    for (int i = 0; i < 2; ++i) {
      const int id = i * 256 + t;
      if (id < 320) {
        const int n = id >> 2, ko = (id & 3) * 8;
        uint4 val = make_uint4(0u, 0u, 0u, 0u);
        if (k0 + ko < 400) val = *(const uint4*)&Bt[(size_t)n * 400 + k0 + ko];
        *(uint4*)&Bs[n][ko] = val;
      }
    }
    __syncthreads();
    v8s a[4], b[5];
#pragma unroll
    for (int ms = 0; ms < 4; ++ms) a[ms] = *(const v8s*)&As[mw + ms * 16 + l16][q * 8];
#pragma unroll
    for (int ns = 0; ns < 5; ++ns) b[ns] = *(const v8s*)&Bs[ns * 16 + l16][q * 8];
#pragma unroll
    for (int ms = 0; ms < 4; ++ms)
#pragma unroll
      for (int ns = 0; ns < 5; ++ns)
        acc[ms][ns] = __builtin_amdgcn_mfma_f32_16x16x32_bf16(a[ms], b[ns], acc[ms][ns], 0, 0, 0);
    __syncthreads();
  }
  // epilogue: D layout col = lane&15, row = q*4 + reg
#pragma unroll
  for (int ms = 0; ms < 4; ++ms)
#pragma unroll
    for (int ns = 0; ns < 5; ++ns) {
      const v4f c = acc[ms][ns];
      const int col = nb + ns * 16 + l16;
#pragma unroll
      for (int reg = 0; reg < 4; ++reg) {
        const int m = m0 + mw + ms * 16 + q * 4 + reg;
        O[(size_t)m * 400 + col] = f2bf(c[reg]);
      }
    }
}

// ---------------------------------------------------------------------------
// K3: fused per-(b,h) self-attention (bf16 q/k/v in, bf16 ctx out).
// ---------------------------------------------------------------------------
__global__ __launch_bounds__(256) void k_attn(const u32* __restrict__ qg,
    const u32* __restrict__ kg, const u32* __restrict__ vg,
    const int* __restrict__ seq, u32* __restrict__ ctxg) {
  const int b = blockIdx.x / HH, h = blockIdx.x % HH;
  const int t = threadIdx.x;
  __shared__ float qs[SS][21], ks[SS][21], vs[SS][20];
  __shared__ float lg[SS][101];
  const int len = seq[b];
  for (int id = t; id < SS * 10; id += 256) {
    const int s = id / 10, pj = id % 10;
    const size_t off = ((size_t)(b * SS + s) * DD + h * DHH) / 2 + (size_t)pj;
    const u32 a = qg[off], c = kg[off], d = vg[off];
    qs[s][pj * 2] = lo2f(a); qs[s][pj * 2 + 1] = hi2f(a);
    ks[s][pj * 2] = lo2f(c); ks[s][pj * 2 + 1] = hi2f(c);
    vs[s][pj * 2] = lo2f(d); vs[s][pj * 2 + 1] = hi2f(d);
  }
  __syncthreads();
  const float sc = 0.2236067977499790f;  // 1/sqrt(20)
  for (int p = t; p < SS * SS; p += 256) {
    const int sq = p / SS, sk = p % SS;
    float acc = 0.f;
#pragma unroll
    for (int j = 0; j < DHH; ++j) acc += qs[sq][j] * ks[sk][j];
    lg[sq][sk] = acc * sc + ((sk < len) ? 1.0f : -1e9f);
  }
  __syncthreads();
  if (t < SS) {
    float mx = -3.0e38f;
    for (int j = 0; j < SS; ++j) mx = fmaxf(mx, lg[t][j]);
    float sum = 0.f;
    for (int j = 0; j < SS; ++j) { const float ex = __expf(lg[t][j] - mx); lg[t][j] = ex; sum += ex; }
    const float inv = 1.0f / sum;
    for (int j = 0; j < SS; ++j) lg[t][j] *= inv;
  }
  __syncthreads();
  for (int id = t; id < SS * 10; id += 256) {
    const int s = id / 10, pj = id % 10;
    float a0 = 0.f, a1 = 0.f;
    for (int kk = 0; kk < SS; ++kk) {
      const float p = lg[s][kk];
      a0 += p * vs[kk][pj * 2];
      a1 += p * vs[kk][pj * 2 + 1];
    }
    ctxg[((size_t)(b * SS + s) * DD + h * DHH) / 2 + (size_t)pj] = packf2(a0, a1);
  }
}

// ---------------------------------------------------------------------------
// K4: e = tanh(ctx @ fc1_w + fc1_b), bf16 MFMA.  A = ctx16 [51200][400],
// Bt = fc1_w^T bf16 [128][400].  Block tile 128M x 64N; 4 waves, each
// 32M x 64N = 2x4 tiles.  grid (400, 2).  e written f32.
// ---------------------------------------------------------------------------
__global__ __launch_bounds__(256) void k_fc1_mfma(const u16* __restrict__ A,
    const u16* __restrict__ Bt, const float* __restrict__ f1b,
    float* __restrict__ e) {
  __shared__ u16 As[128][40];
  __shared__ u16 Bs[64][40];
  const int t = threadIdx.x;
  const int wave = t >> 6, lane = t & 63;
  const int q = lane >> 4, l16 = lane & 15;
  const int m0 = blockIdx.x * 128;
  const int nb = blockIdx.y * 64;
  const int mw = wave * 32;
  v4f acc[2][4];
#pragma unroll
  for (int i = 0; i < 2; ++i)
#pragma unroll
    for (int j = 0; j < 4; ++j) acc[i][j] = (v4f){0.f, 0.f, 0.f, 0.f};

  for (int kt = 0; kt < 13; ++kt) {
    const int k0 = kt * 32;
#pragma unroll
    for (int i = 0; i < 2; ++i) {           // A: 128 x 32 = 512 16B-loads
      const int id = i * 256 + t;
      const int r = id >> 2, ko = (id & 3) * 8;
      uint4 val = make_uint4(0u, 0u, 0u, 0u);
      if (k0 + ko < 400) val = *(const uint4*)&A[(size_t)(m0 + r) * 400 + k0 + ko];
      *(uint4*)&As[r][ko] = val;
    }
    {                                        // B: 64 x 32 = 256 16B-loads
      const int r = t >> 2, ko = (t & 3) * 8;
      uint4 val = make_uint4(0u, 0u, 0u, 0u);
      if (k0 + ko < 400) val = *(const uint4*)&Bt[(size_t)(nb + r) * 400 + k0 + ko];
      *(uint4*)&Bs[r][ko] = val;
    }
    __syncthreads();
    v8s a[2], b[4];
#pragma unroll
    for (int ms = 0; ms < 2; ++ms) a[ms] = *(const v8s*)&As[mw + ms * 16 + l16][q * 8];
#pragma unroll
    for (int ns = 0; ns < 4; ++ns) b[ns] = *(const v8s*)&Bs[ns * 16 + l16][q * 8];
#pragma unroll
    for (int ms = 0; ms < 2; ++ms)
#pragma unroll
      for (int ns = 0; ns < 4; ++ns)
        acc[ms][ns] = __builtin_amdgcn_mfma_f32_16x16x32_bf16(a[ms], b[ns], acc[ms][ns], 0, 0, 0);
    __syncthreads();
  }
#pragma unroll
  for (int ms = 0; ms < 2; ++ms)
#pragma unroll
    for (int ns = 0; ns < 4; ++ns) {
      const v4f c = acc[ms][ns];
      const int col = nb + ns * 16 + l16;
      const float bias = f1b[col];
#pragma unroll
      for (int reg = 0; reg < 4; ++reg) {
        const int m = m0 + mw + ms * 16 + q * 4 + reg;
        e[(size_t)m * MM + col] = tanhf(c[reg] + bias);
      }
    }
}

// ---------------------------------------------------------------------------
// K5: additive attention pooling.  One block per batch row.
// e f32, ctx bf16, out f32.
// ---------------------------------------------------------------------------
__global__ __launch_bounds__(256) void k_pool(const float* __restrict__ e,
    const float* __restrict__ f2w, const float* __restrict__ f2b,
    const int* __restrict__ seq, const u16* __restrict__ ctxg,
    float* __restrict__ out) {
  const int b = blockIdx.x;
  const int t = threadIdx.x, w = t >> 6, lane = t & 63;
  __shared__ float wts[SS];
  __shared__ float fw[MM];
  if (t < MM) fw[t] = f2w[t];
  __syncthreads();
  const int len = seq[b];
  const float bias = f2b[0];
  for (int s = w; s < SS; s += 4) {
    const float* er = e + (size_t)(b * SS + s) * MM;
    float p = er[lane] * fw[lane] + er[lane + 64] * fw[lane + 64];
#pragma unroll
    for (int o = 32; o > 0; o >>= 1) p += __shfl_down(p, o);
    if (lane == 0) wts[s] = p + bias + ((s < len) ? 1.0f : -1e9f);
  }
  __syncthreads();
  if (w == 0) {
    const float v0 = wts[lane];
    const float v1 = (lane + 64 < SS) ? wts[lane + 64] : -3.0e38f;
    float mx = fmaxf(v0, v1);
#pragma unroll
    for (int o = 32; o > 0; o >>= 1) mx = fmaxf(mx, __shfl_xor(mx, o));
    const float e0 = __expf(v0 - mx);
    const float e1 = (lane + 64 < SS) ? __expf(v1 - mx) : 0.f;
    float sm = e0 + e1;
#pragma unroll
    for (int o = 32; o > 0; o >>= 1) sm += __shfl_xor(sm, o);
    const float inv = 1.0f / sm;
    wts[lane] = e0 * inv;
    if (lane + 64 < SS) wts[lane + 64] = e1 * inv;
  }
  __syncthreads();
  for (int d = t; d < DD; d += 256) {
    float acc = 0.f;
    const u16* cb = ctxg + (size_t)b * SS * DD + d;
    for (int s = 0; s < SS; ++s) acc += wts[s] * bf2f(cb[(size_t)s * DD]);
    out[(size_t)b * DD + d] = acc;
  }
}

// ---------------------------------------------------------------------------
// Workspace (~205 MB; ws >= 328 MB established in R4):
//   emb16   [50000][400] bf16   (40.00 MB)
//   wt      [1200][400]  bf16   ( 0.96 MB)  wq^T | wk^T | wv^T
//   wtf     [128][400]   bf16   ( 0.10 MB)  fc1_w^T
//   click16 [51200][400] bf16   (40.96 MB)  -> overwritten by ctx16
//   q16/k16/v16 same size        (3x40.96 MB); e (f32, 26.2 MB) overlays q16
// ---------------------------------------------------------------------------
extern "C" void kernel_launch(void* const* d_in, const int* in_sizes, int n_in,
                              void* d_out, int out_size, void* d_ws, size_t ws_size,
                              hipStream_t stream) {
  const int*   uc  = (const int*)d_in[0];
  const int*   seq = (const int*)d_in[1];
  const float* emb = (const float*)d_in[2];
  const float* wq  = (const float*)d_in[3];
  const float* wk  = (const float*)d_in[4];
  const float* wv  = (const float*)d_in[5];
  const float* f1w = (const float*)d_in[6];
  const float* f1b = (const float*)d_in[7];
  const float* f2w = (const float*)d_in[8];
  const float* f2b = (const float*)d_in[9];
  float* out = (float*)d_out;

  u16* emb16   = (u16*)d_ws;
  u16* wt      = emb16 + 20000000ull;          // 1200*400
  u16* wtf     = wt + 480000ull;               // 128*400
  u16* click16 = wtf + 51200ull;               // also ctx16
  u16* q16     = click16 + 20480000ull;
  u16* k16     = q16 + 20480000ull;
  u16* v16     = k16 + 20480000ull;
  float* e     = (float*)q16;                  // q dead after attn

  k_cvt<<<(5000000 + 255) / 256, 256, 0, stream>>>(emb, emb16, 5000000);
  k_trans<<<dim3(13, 13), 256, 0, stream>>>(wq, wt, 400, 400);
  k_trans<<<dim3(13, 13), 256, 0, stream>>>(wk, wt + 160000, 400, 400);
  k_trans<<<dim3(13, 13), 256, 0, stream>>>(wv, wt + 320000, 400, 400);
  k_trans<<<dim3(4, 13), 256, 0, stream>>>(f1w, wtf, 400, 128);
  k_embed<<<12800, 256, 0, stream>>>(uc, emb16, (u32*)click16);
  k_qkv_mfma<<<dim3(200, 15), 256, 0, stream>>>(click16, wt, q16, k16, v16);
  k_attn<<<BB * HH, 256, 0, stream>>>((const u32*)q16, (const u32*)k16,
                                      (const u32*)v16, seq, (u32*)click16);
  k_fc1_mfma<<<dim3(400, 2), 256, 0, stream>>>(click16, wtf, f1b, e);
  k_pool<<<BB, 256, 0, stream>>>(e, f2w, f2b, seq, click16, out);
}

// Round 6
// 660.493 us; speedup vs baseline: 3.9984x; 1.5890x over previous
//
#include <hip/hip_runtime.h>
#include <hip/hip_bf16.h>

using u16 = unsigned short;
using u32 = unsigned int;

#define BB 512
#define SS 100
#define LL 30
#define DD 400
#define MM 128
#define HH 20
#define DHH 20

typedef short v8s __attribute__((ext_vector_type(8)));   // 8 bf16 = 4 VGPR
typedef float v4f __attribute__((ext_vector_type(4)));   // MFMA 16x16 acc

__device__ __forceinline__ float lo2f(u32 u) { return __uint_as_float(u << 16); }
__device__ __forceinline__ float hi2f(u32 u) { return __uint_as_float(u & 0xffff0000u); }
__device__ __forceinline__ float bf2f(u16 h) { return __uint_as_float(((u32)h) << 16); }
__device__ __forceinline__ u16 f2bf(float f) {
  u32 u = __float_as_uint(f);
  u += 0x7fffu + ((u >> 16) & 1u);
  return (u16)(u >> 16);
}
__device__ __forceinline__ u32 packf2(float a, float b) {
  return (u32)f2bf(a) | (((u32)f2bf(b)) << 16);
}

// ---------------------------------------------------------------------------
// K0a: f32 -> bf16 bulk convert (emb table).  n4 = elements/4.
// ---------------------------------------------------------------------------
__global__ __launch_bounds__(256) void k_cvt(const float* __restrict__ src,
                                             u16* __restrict__ dst, int n4) {
  const int i = blockIdx.x * 256 + threadIdx.x;
  if (i < n4) {
    const float4 v = ((const float4*)src)[i];
    ((uint2*)dst)[i] = make_uint2(packf2(v.x, v.y), packf2(v.z, v.w));
  }
}

// ---------------------------------------------------------------------------
// K0b: transpose-convert  src f32 [K][N]  ->  dst bf16 [N][K].
// ---------------------------------------------------------------------------
__global__ __launch_bounds__(256) void k_trans(const float* __restrict__ src,
                                               u16* __restrict__ dst, int K, int N) {
  __shared__ float ts[32][33];
  const int t = threadIdx.x;
  const int n0 = blockIdx.x * 32, k0 = blockIdx.y * 32;
  const int c = t & 31, r8 = t >> 5;
#pragma unroll
  for (int i = 0; i < 4; ++i) {
    const int k = k0 + r8 + i * 8, n = n0 + c;
    ts[r8 + i * 8][c] = (k < K && n < N) ? src[(size_t)k * N + n] : 0.f;
  }
  __syncthreads();
#pragma unroll
  for (int i = 0; i < 4; ++i) {
    const int n = n0 + r8 + i * 8, k = k0 + c;
    if (n < N && k < K) dst[(size_t)n * K + k] = f2bf(ts[c][r8 + i * 8]);
  }
}

// ---------------------------------------------------------------------------
// K1: embedding gather + mean pool (bf16 table).  wave-per-(b,s) row.
// ---------------------------------------------------------------------------
__global__ __launch_bounds__(256) void k_embed(const int* __restrict__ uc,
                                               const u16* __restrict__ emb,
                                               u32* __restrict__ click) {
  const int wave = threadIdx.x >> 6, lane = threadIdx.x & 63;
  const int bs = blockIdx.x * 4 + wave;
  __shared__ int rows[4][LL];
  if (lane < LL) rows[wave][lane] = uc[(size_t)bs * LL + lane];
  __syncthreads();
  float ax[4] = {0.f, 0.f, 0.f, 0.f}, ay[4] = {0.f, 0.f, 0.f, 0.f};
  for (int l = 0; l < LL; ++l) {
    const u32* row = (const u32*)(emb + (size_t)rows[wave][l] * DD);
    const u32 a = row[lane], b = row[lane + 64], c = row[lane + 128];
    ax[0] += lo2f(a); ay[0] += hi2f(a);
    ax[1] += lo2f(b); ay[1] += hi2f(b);
    ax[2] += lo2f(c); ay[2] += hi2f(c);
    if (lane < 8) { const u32 d = row[lane + 192]; ax[3] += lo2f(d); ay[3] += hi2f(d); }
  }
  const float s = 1.0f / (float)LL;
  u32* orow = click + (size_t)bs * 200;
  orow[lane]       = packf2(ax[0] * s, ay[0] * s);
  orow[lane + 64]  = packf2(ax[1] * s, ay[1] * s);
  orow[lane + 128] = packf2(ax[2] * s, ay[2] * s);
  if (lane < 8) orow[lane + 192] = packf2(ax[3] * s, ay[3] * s);
}

// ---------------------------------------------------------------------------
// K2: QKV projection, bf16 MFMA (unchanged from R5 — verified).
// ---------------------------------------------------------------------------
__global__ __launch_bounds__(256) void k_qkv_mfma(const u16* __restrict__ A,
    const u16* __restrict__ Wt, u16* __restrict__ qo, u16* __restrict__ ko_,
    u16* __restrict__ vo) {
  __shared__ u16 As[256][40];
  __shared__ u16 Bs[80][40];
  const int t = threadIdx.x;
  const int wave = t >> 6, lane = t & 63;
  const int q = lane >> 4, l16 = lane & 15;
  const int m0 = blockIdx.x * 256;
  const int mat = blockIdx.y / 5, ntile = blockIdx.y % 5;
  const int nb = ntile * 80;
  const u16* Bt = Wt + (size_t)(mat * 400 + nb) * 400;
  u16* O = (mat == 0) ? qo : ((mat == 1) ? ko_ : vo);
  const int mw = wave * 64;

  v4f acc[4][5];
#pragma unroll
  for (int i = 0; i < 4; ++i)
#pragma unroll
    for (int j = 0; j < 5; ++j) acc[i][j] = (v4f){0.f, 0.f, 0.f, 0.f};

  for (int kt = 0; kt < 13; ++kt) {
    const int k0 = kt * 32;
#pragma unroll
    for (int i = 0; i < 4; ++i) {
      const int id = i * 256 + t;
      const int r = id >> 2, ko = (id & 3) * 8;
      uint4 val = make_uint4(0u, 0u, 0u, 0u);
      if (k0 + ko < 400) val = *(const uint4*)&A[(size_t)(m0 + r) * 400 + k0 + ko];
      *(uint4*)&As[r][ko] = val;
    }
#pragma unroll
    for (int i = 0; i < 2; ++i) {
      const int id = i * 256 + t;
      if (id < 320) {
        const int n = id >> 2, ko = (id & 3) * 8;
        uint4 val = make_uint4(0u, 0u, 0u, 0u);
        if (k0 + ko < 400) val = *(const uint4*)&Bt[(size_t)n * 400 + k0 + ko];
        *(uint4*)&Bs[n][ko] = val;
      }
    }
    __syncthreads();
    v8s a[4], b[5];
#pragma unroll
    for (int ms = 0; ms < 4; ++ms) a[ms] = *(const v8s*)&As[mw + ms * 16 + l16][q * 8];
#pragma unroll
    for (int ns = 0; ns < 5; ++ns) b[ns] = *(const v8s*)&Bs[ns * 16 + l16][q * 8];
#pragma unroll
    for (int ms = 0; ms < 4; ++ms)
#pragma unroll
      for (int ns = 0; ns < 5; ++ns)
        acc[ms][ns] = __builtin_amdgcn_mfma_f32_16x16x32_bf16(a[ms], b[ns], acc[ms][ns], 0, 0, 0);
    __syncthreads();
  }
#pragma unroll
  for (int ms = 0; ms < 4; ++ms)
#pragma unroll
    for (int ns = 0; ns < 5; ++ns) {
      const v4f c = acc[ms][ns];
      const int col = nb + ns * 16 + l16;
#pragma unroll
      for (int reg = 0; reg < 4; ++reg) {
        const int m = m0 + mw + ms * 16 + q * 4 + reg;
        O[(size_t)m * 400 + col] = f2bf(c[reg]);
      }
    }
}

// ---------------------------------------------------------------------------
// K3: MFMA attention.  One block per (b,h), 4 waves.
//   S = Q·K^T  (M=100->112, N=100->112, K=20->32; 7x7 16x16 tiles)
//   softmax in registers on C-layout rows (shfl_xor over the 16-lane group)
//   P (bf16) -> LDS in A-frag order; ctx = P·V^T-frag (K=100->128, 4 chunks)
// LDS strides padded (40 / 136 u16) -> 2 lanes/bank = conflict-free.
// ---------------------------------------------------------------------------
__global__ __launch_bounds__(256) void k_attn_mfma(const u16* __restrict__ qg,
    const u16* __restrict__ kg, const u16* __restrict__ vg,
    const int* __restrict__ seq, u16* __restrict__ ctxg) {
  __shared__ u16 Qs[112][40];
  __shared__ u16 Ks[112][40];
  __shared__ u16 Vs[112][40];
  __shared__ u16 Vt[32][136];
  __shared__ u16 Ss[112][136];
  const int b = blockIdx.x / HH, h = blockIdx.x % HH;
  const int t = threadIdx.x;
  const int wave = t >> 6, lane = t & 63;
  const int quad = lane >> 4, l16 = lane & 15;
  const int len = seq[b];
  const u16* qb = qg + (size_t)b * SS * DD + h * DHH;
  const u16* kb = kg + (size_t)b * SS * DD + h * DHH;
  const u16* vb = vg + (size_t)b * SS * DD + h * DHH;
  // stage Q,K,V: 112 rows x 8 chunks of 4 bf16 (cols 20..31 + rows 100.. zero)
  for (int id = t; id < 896; id += 256) {
    const int r = id >> 3, ch = id & 7;
    uint2 vq = make_uint2(0u, 0u), vk = vq, vv = vq;
    if (r < 100 && ch < 5) {
      vq = *(const uint2*)(qb + (size_t)r * DD + ch * 4);
      vk = *(const uint2*)(kb + (size_t)r * DD + ch * 4);
      vv = *(const uint2*)(vb + (size_t)r * DD + ch * 4);
    }
    *(uint2*)&Qs[r][ch * 4] = vq;
    *(uint2*)&Ks[r][ch * 4] = vk;
    *(uint2*)&Vs[r][ch * 4] = vv;
  }
  // zero pads (disjoint from later fills): Vt rows 20-31; Vt cols 100-135;
  // Ss cols 112-127 (read by PV k-chunk 3).
  for (int id = t; id < 816; id += 256) ((u32*)&Vt[20][0])[id] = 0u;
  for (int id = t; id < 360; id += 256) {
    const int r = id / 18, c = id % 18;
    *(u32*)&Vt[r][100 + c * 2] = 0u;
  }
  for (int id = t; id < 896; id += 256) {
    const int r = id >> 3, c = id & 7;
    *(u32*)&Ss[r][112 + c * 2] = 0u;
  }
  __syncthreads();
  // transpose Vs -> Vt (d<20, key<100); completes before barrier 2
  for (int id = t; id < 2000; id += 256) {
    const int d = id / 100, key = id % 100;
    Vt[d][key] = Vs[key][d];
  }
  // QK^T + row softmax.  wave handles m-tiles {wave, wave+4}
  const float sc = 0.2236067977499790f;  // 1/sqrt(20)
  for (int mi = 0; mi < 2; ++mi) {
    const int mt = wave + mi * 4;
    if (mt >= 7) break;
    const v8s a = *(const v8s*)&Qs[mt * 16 + l16][quad * 8];
    v4f acc[7];
#pragma unroll
    for (int nt = 0; nt < 7; ++nt) {
      const v8s bk = *(const v8s*)&Ks[nt * 16 + l16][quad * 8];
      acc[nt] = __builtin_amdgcn_mfma_f32_16x16x32_bf16(a, bk, (v4f){0.f,0.f,0.f,0.f}, 0, 0, 0);
    }
#pragma unroll
    for (int reg = 0; reg < 4; ++reg) {
      float v[7];
      float mx = -3.0e38f;
#pragma unroll
      for (int nt = 0; nt < 7; ++nt) {
        const int col = nt * 16 + l16;
        v[nt] = acc[nt][reg] * sc + ((col < len) ? 1.0f : -1e9f);
        mx = fmaxf(mx, v[nt]);
      }
#pragma unroll
      for (int o = 1; o < 16; o <<= 1) mx = fmaxf(mx, __shfl_xor(mx, o));
      float sum = 0.f;
#pragma unroll
      for (int nt = 0; nt < 7; ++nt) { v[nt] = __expf(v[nt] - mx); sum += v[nt]; }
#pragma unroll
      for (int o = 1; o < 16; o <<= 1) sum += __shfl_xor(sum, o);
      const float inv = 1.0f / sum;
      const int row = mt * 16 + quad * 4 + reg;
#pragma unroll
      for (int nt = 0; nt < 7; ++nt) Ss[row][nt * 16 + l16] = f2bf(v[nt] * inv);
    }
  }
  __syncthreads();
  // PV: ctx[q][d] = sum_k P[q][k] V[k][d];  B-frag rows = Vt[d][key]
  u16* cb = ctxg + (size_t)b * SS * DD + h * DHH;
  for (int mi = 0; mi < 2; ++mi) {
    const int mt = wave + mi * 4;
    if (mt >= 7) break;
    v4f o0 = (v4f){0.f,0.f,0.f,0.f}, o1 = o0;
#pragma unroll
    for (int kc = 0; kc < 4; ++kc) {
      const v8s a  = *(const v8s*)&Ss[mt * 16 + l16][kc * 32 + quad * 8];
      const v8s b0 = *(const v8s*)&Vt[l16][kc * 32 + quad * 8];
      const v8s b1 = *(const v8s*)&Vt[16 + l16][kc * 32 + quad * 8];
      o0 = __builtin_amdgcn_mfma_f32_16x16x32_bf16(a, b0, o0, 0, 0, 0);
      o1 = __builtin_amdgcn_mfma_f32_16x16x32_bf16(a, b1, o1, 0, 0, 0);
    }
#pragma unroll
    for (int reg = 0; reg < 4; ++reg) {
      const int q = mt * 16 + quad * 4 + reg;
      if (q < 100) {
        cb[(size_t)q * DD + l16] = f2bf(o0[reg]);
        if (l16 < 4) cb[(size_t)q * DD + 16 + l16] = f2bf(o1[reg]);
      }
    }
  }
}

// ---------------------------------------------------------------------------
// K4: e = tanh(ctx @ fc1_w + fc1_b), bf16 MFMA (unchanged from R5).
// ---------------------------------------------------------------------------
__global__ __launch_bounds__(256) void k_fc1_mfma(const u16* __restrict__ A,
    const u16* __restrict__ Bt, const float* __restrict__ f1b,
    float* __restrict__ e) {
  __shared__ u16 As[128][40];
  __shared__ u16 Bs[64][40];
  const int t = threadIdx.x;
  const int wave = t >> 6, lane = t & 63;
  const int q = lane >> 4, l16 = lane & 15;
  const int m0 = blockIdx.x * 128;
  const int nb = blockIdx.y * 64;
  const int mw = wave * 32;
  v4f acc[2][4];
#pragma unroll
  for (int i = 0; i < 2; ++i)
#pragma unroll
    for (int j = 0; j < 4; ++j) acc[i][j] = (v4f){0.f, 0.f, 0.f, 0.f};

  for (int kt = 0; kt < 13; ++kt) {
    const int k0 = kt * 32;
#pragma unroll
    for (int i = 0; i < 2; ++i) {
      const int id = i * 256 + t;
      const int r = id >> 2, ko = (id & 3) * 8;
      uint4 val = make_uint4(0u, 0u, 0u, 0u);
      if (k0 + ko < 400) val = *(const uint4*)&A[(size_t)(m0 + r) * 400 + k0 + ko];
      *(uint4*)&As[r][ko] = val;
    }
    {
      const int r = t >> 2, ko = (t & 3) * 8;
      uint4 val = make_uint4(0u, 0u, 0u, 0u);
      if (k0 + ko < 400) val = *(const uint4*)&Bt[(size_t)(nb + r) * 400 + k0 + ko];
      *(uint4*)&Bs[r][ko] = val;
    }
    __syncthreads();
    v8s a[2], b[4];
#pragma unroll
    for (int ms = 0; ms < 2; ++ms) a[ms] = *(const v8s*)&As[mw + ms * 16 + l16][q * 8];
#pragma unroll
    for (int ns = 0; ns < 4; ++ns) b[ns] = *(const v8s*)&Bs[ns * 16 + l16][q * 8];
#pragma unroll
    for (int ms = 0; ms < 2; ++ms)
#pragma unroll
      for (int ns = 0; ns < 4; ++ns)
        acc[ms][ns] = __builtin_amdgcn_mfma_f32_16x16x32_bf16(a[ms], b[ns], acc[ms][ns], 0, 0, 0);
    __syncthreads();
  }
#pragma unroll
  for (int ms = 0; ms < 2; ++ms)
#pragma unroll
    for (int ns = 0; ns < 4; ++ns) {
      const v4f c = acc[ms][ns];
      const int col = nb + ns * 16 + l16;
      const float bias = f1b[col];
#pragma unroll
      for (int reg = 0; reg < 4; ++reg) {
        const int m = m0 + mw + ms * 16 + q * 4 + reg;
        e[(size_t)m * MM + col] = tanhf(c[reg] + bias);
      }
    }
}

// ---------------------------------------------------------------------------
// K5: additive attention pooling (unchanged from R5).
// ---------------------------------------------------------------------------
__global__ __launch_bounds__(256) void k_pool(const float* __restrict__ e,
    const float* __restrict__ f2w, const float* __restrict__ f2b,
    const int* __restrict__ seq, const u16* __restrict__ ctxg,
    float* __restrict__ out) {
  const int b = blockIdx.x;
  const int t = threadIdx.x, w = t >> 6, lane = t & 63;
  __shared__ float wts[SS];
  __shared__ float fw[MM];
  if (t < MM) fw[t] = f2w[t];
  __syncthreads();
  const int len = seq[b];
  const float bias = f2b[0];
  for (int s = w; s < SS; s += 4) {
    const float* er = e + (size_t)(b * SS + s) * MM;
    float p = er[lane] * fw[lane] + er[lane + 64] * fw[lane + 64];
#pragma unroll
    for (int o = 32; o > 0; o >>= 1) p += __shfl_down(p, o);
    if (lane == 0) wts[s] = p + bias + ((s < len) ? 1.0f : -1e9f);
  }
  __syncthreads();
  if (w == 0) {
    const float v0 = wts[lane];
    const float v1 = (lane + 64 < SS) ? wts[lane + 64] : -3.0e38f;
    float mx = fmaxf(v0, v1);
#pragma unroll
    for (int o = 32; o > 0; o >>= 1) mx = fmaxf(mx, __shfl_xor(mx, o));
    const float e0 = __expf(v0 - mx);
    const float e1 = (lane + 64 < SS) ? __expf(v1 - mx) : 0.f;
    float sm = e0 + e1;
#pragma unroll
    for (int o = 32; o > 0; o >>= 1) sm += __shfl_xor(sm, o);
    const float inv = 1.0f / sm;
    wts[lane] = e0 * inv;
    if (lane + 64 < SS) wts[lane + 64] = e1 * inv;
  }
  __syncthreads();
  for (int d = t; d < DD; d += 256) {
    float acc = 0.f;
    const u16* cb = ctxg + (size_t)b * SS * DD + d;
    for (int s = 0; s < SS; ++s) acc += wts[s] * bf2f(cb[(size_t)s * DD]);
    out[(size_t)b * DD + d] = acc;
  }
}

// ---------------------------------------------------------------------------
extern "C" void kernel_launch(void* const* d_in, const int* in_sizes, int n_in,
                              void* d_out, int out_size, void* d_ws, size_t ws_size,
                              hipStream_t stream) {
  const int*   uc  = (const int*)d_in[0];
  const int*   seq = (const int*)d_in[1];
  const float* emb = (const float*)d_in[2];
  const float* wq  = (const float*)d_in[3];
  const float* wk  = (const float*)d_in[4];
  const float* wv  = (const float*)d_in[5];
  const float* f1w = (const float*)d_in[6];
  const float* f1b = (const float*)d_in[7];
  const float* f2w = (const float*)d_in[8];
  const float* f2b = (const float*)d_in[9];
  float* out = (float*)d_out;

  u16* emb16   = (u16*)d_ws;
  u16* wt      = emb16 + 20000000ull;
  u16* wtf     = wt + 480000ull;
  u16* click16 = wtf + 51200ull;               // also ctx16
  u16* q16     = click16 + 20480000ull;
  u16* k16     = q16 + 20480000ull;
  u16* v16     = k16 + 20480000ull;
  float* e     = (float*)q16;                  // q dead after attn

  k_cvt<<<(5000000 + 255) / 256, 256, 0, stream>>>(emb, emb16, 5000000);
  k_trans<<<dim3(13, 13), 256, 0, stream>>>(wq, wt, 400, 400);
  k_trans<<<dim3(13, 13), 256, 0, stream>>>(wk, wt + 160000, 400, 400);
  k_trans<<<dim3(13, 13), 256, 0, stream>>>(wv, wt + 320000, 400, 400);
  k_trans<<<dim3(4, 13), 256, 0, stream>>>(f1w, wtf, 400, 128);
  k_embed<<<12800, 256, 0, stream>>>(uc, emb16, (u32*)click16);
  k_qkv_mfma<<<dim3(200, 15), 256, 0, stream>>>(click16, wt, q16, k16, v16);
  k_attn_mfma<<<BB * HH, 256, 0, stream>>>(q16, k16, v16, seq, click16);
  k_fc1_mfma<<<dim3(400, 2), 256, 0, stream>>>(click16, wtf, f1b, e);
  k_pool<<<BB, 256, 0, stream>>>(e, f2w, f2b, seq, click16, out);
}